// Round 4
// baseline (787.093 us; speedup 1.0000x reference)
//
#include <hip/hip_runtime.h>

// SSIM on (32,3,512,512) f32 — wave-autonomous separable 11-tap streaming.
// Structure (R8): shift-register vertical conv; branchless hot loop with
// clamped loads + validity-multiply; LDS packed float4 (xA,xB,yA,yB) ->
// 7 ds_read_b128/step; 4 wave-private bands per 256-thread block.
// Each wave: 128 cols x 64 rows; lanes hold 2 cols. No hot-loop barriers.
//
// Occupancy saga:
//  R9  (256,4): HIP doubles arg -> 8-wave/EU reg limit 64 -> 3GB spill.
//  R10 (256,3): limit 85 (6 waves) -> VGPR 84, spilled, BUT packed 3 blk/CU.
//  R11 attr(2,4): limit 256, VGPR 120 spill-free, but packed 2 blk/CU again.
//  Model fitting all 4 points: HW packs by the ALLOCATED budget (512/min
//  metadata waves), not by used VGPRs: budget 256->2 blk, 170->3, 128->4.
// R12: attr(3,4): codegen limit 512/3=170 >= 120 live -> NO spill possible,
//  allocation 170 -> 3 blocks/CU = grid 768/256 exactly: all blocks
//  co-resident, single phase, zero tail. Predict VALUBusy ~70%+, ~105us.

#define NBLK 768

__device__ __forceinline__ float2 f2z() { return make_float2(0.f, 0.f); }
__device__ __forceinline__ float2 fma2(float s, float2 a, float2 c) {
    return make_float2(fmaf(s, a.x, c.x), fmaf(s, a.y, c.y));
}
__device__ __forceinline__ float2 mul2(float s, float2 a) {
    return make_float2(s * a.x, s * a.y);
}

// ---- vertical shift-register chains: 10 regs x 5 quantities (float2 A/B) ----
#define DECL_CH(C) float2 C##0=f2z(),C##1=f2z(),C##2=f2z(),C##3=f2z(),C##4=f2z(), \
                          C##5=f2z(),C##6=f2z(),C##7=f2z(),C##8=f2z(),C##9=f2z();
// descending: each reads the not-yet-overwritten lower element
#define SHIFT(C, H) \
  C##9 = fma2(g9, H, C##8); C##8 = fma2(g8, H, C##7); C##7 = fma2(g7, H, C##6); \
  C##6 = fma2(g6, H, C##5); C##5 = fma2(g5, H, C##4); C##4 = fma2(g4, H, C##3); \
  C##3 = fma2(g3, H, C##2); C##2 = fma2(g2, H, C##1); C##1 = fma2(g1, H, C##0); \
  C##0 = mul2(g0, H);

// ---- horizontal tap J: colA uses val[J+1], colB val[J+2] ----
#define HTAP(J, UA, UB) { const float gj = g##J; \
  { const float xv = XV##UA, yv = YV##UA; const float t1 = gj*xv, t2 = gj*yv; \
    HX.x += t1; HY.x += t2; HXX.x = fmaf(t1,xv,HXX.x); HYY.x = fmaf(t2,yv,HYY.x); HXY.x = fmaf(t1,yv,HXY.x); } \
  { const float xv = XV##UB, yv = YV##UB; const float t1 = gj*xv, t2 = gj*yv; \
    HX.y += t1; HY.y += t2; HXX.y = fmaf(t1,xv,HXX.y); HYY.y = fmaf(t2,yv,HYY.y); HXY.y = fmaf(t1,yv,HXY.y); } }

#define SSIM_COL(MU_X, MU_Y, SXX, SYY, SXY, TS) { \
  const float mux = MU_X, muy = MU_Y; \
  const float mux2 = mux*mux, muy2 = muy*muy, muxy = mux*muy; \
  const float vvx = SXX - mux2, vvy = SYY - muy2, vxy = SXY - muxy; \
  const float num = fmaf(2.f, muxy, C1) * fmaf(2.f, vxy, C2); \
  const float den = (mux2 + muy2 + C1) * (vvx + vvy + C2); \
  TS += num * __builtin_amdgcn_rcpf(den); }

// One step: issue PF slot P (row r0-2+i), compute h-conv of current LDS row,
// chain-shift, emit if 10<=i<74, then store PF slot Q (issued 2 steps ago).
#define STEP(I, P, Q) { \
  const int i_ = (I); \
  const int rl = r0 - 2 + i_; \
  VM##P = ((unsigned)rl < 512u) ? 1.f : 0.f; \
  { const int rlc = (rl < 0) ? 0 : ((rl > 511) ? 511 : rl); \
    const float* xp = xplane + (rlc << 9); \
    const float* yp = yplane + (rlc << 9); \
    PF##P##mx = *(const float2*)(xp + mcol); PF##P##my = *(const float2*)(yp + mcol); \
    PF##P##hx = *(const float2*)(xp + hcolC); PF##P##hy = *(const float2*)(yp + hcolC); } \
  const float4 q0 = lsw[lane  ], q1 = lsw[lane+1], q2 = lsw[lane+2], q3 = lsw[lane+3]; \
  const float4 q4 = lsw[lane+4], q5 = lsw[lane+5], q6 = lsw[lane+6]; \
  const float XV1 = q0.y, XV2 = q1.x, XV3 = q1.y, XV4 = q2.x, XV5 = q2.y, XV6 = q3.x; \
  const float XV7 = q3.y, XV8 = q4.x, XV9 = q4.y, XV10 = q5.x, XV11 = q5.y, XV12 = q6.x; \
  const float YV1 = q0.w, YV2 = q1.z, YV3 = q1.w, YV4 = q2.z, YV5 = q2.w, YV6 = q3.z; \
  const float YV7 = q3.w, YV8 = q4.z, YV9 = q4.w, YV10 = q5.z, YV11 = q5.w, YV12 = q6.z; \
  float2 HX = f2z(), HY = f2z(), HXX = f2z(), HYY = f2z(), HXY = f2z(); \
  HTAP(0,1,2)  HTAP(1,2,3)  HTAP(2,3,4)  HTAP(3,4,5)  HTAP(4,5,6)  HTAP(5,6,7) \
  HTAP(6,7,8)  HTAP(7,8,9)  HTAP(8,9,10) HTAP(9,10,11) HTAP(10,11,12) \
  if (i_ >= 10 && i_ < 74) { \
    const float2 EX  = fma2(g10, HX , CX9 ); \
    const float2 EY  = fma2(g10, HY , CY9 ); \
    const float2 EXX = fma2(g10, HXX, CXX9); \
    const float2 EYY = fma2(g10, HYY, CYY9); \
    const float2 EXY = fma2(g10, HXY, CXY9); \
    SSIM_COL(EX.x, EY.x, EXX.x, EYY.x, EXY.x, tsx) \
    SSIM_COL(EX.y, EY.y, EXX.y, EYY.y, EXY.y, tsy) \
  } \
  SHIFT(CX, HX) SHIFT(CY, HY) SHIFT(CXX, HXX) SHIFT(CYY, HYY) SHIFT(CXY, HXY) \
  { const float fq = VM##Q; const float fh = fq * hmask; \
    const float2 wmx = mul2(fq, PF##Q##mx), wmy = mul2(fq, PF##Q##my); \
    const float2 whx = mul2(fh, PF##Q##hx), why = mul2(fh, PF##Q##hy); \
    lsw[lane + 3] = make_float4(wmx.x, wmx.y, wmy.x, wmy.y); \
    if (lane < 6) lsw[hslot] = make_float4(whx.x, whx.y, why.x, why.y); } }

__global__ __launch_bounds__(256)
__attribute__((amdgpu_waves_per_eu(3, 4)))
void ssim_fused(
    const float* __restrict__ x, const float* __restrict__ y,
    const float* __restrict__ window,
    unsigned* __restrict__ counter, float* __restrict__ partials,
    float* __restrict__ out)
{
    const int tid  = threadIdx.x;
    const int lane = tid & 63;
    const int wv   = tid >> 6;
    const int W    = blockIdx.x * 4 + wv;   // 0..3071
    const int img  = W >> 5;                // 96 planes
    const int cb   = (W >> 3) & 3;          // 4 col bands x 128
    const int rb   = W & 7;                 // 8 row bands x 64
    const int r0   = rb << 6;
    const int c0   = cb << 7;

    const float* xplane = x + (size_t)img * 262144;
    const float* yplane = y + (size_t)img * 262144;

    // halo geometry (time-invariant): slots 0..2 left, 67..69 right
    const int  hslot = (lane < 3) ? lane : (64 + lane);
    const int  hcol  = (lane < 3) ? (c0 - 6 + 2 * lane)
                                  : (c0 + 128 + 2 * (lane - 3));
    const float hmask = (lane < 6 && hcol >= 0 && hcol < 511) ? 1.f : 0.f;
    const int  hcolC = (hcol < 0) ? 0 : ((hcol > 510) ? 510 : hcol);
    const int  mcol  = c0 + 2 * lane;

    // 1-D gaussian (row sums of outer(g,g)); uniform -> SGPR via readfirstlane
    float gtmp[11];
    #pragma unroll
    for (int ii = 0; ii < 11; ++ii) {
        float s = 0.f;
        #pragma unroll
        for (int jj = 0; jj < 11; ++jj) s += window[ii * 11 + jj];
        gtmp[ii] = s;
    }
    #define SG(N) const float g##N = __uint_as_float(__builtin_amdgcn_readfirstlane(__float_as_uint(gtmp[N])));
    SG(0) SG(1) SG(2) SG(3) SG(4) SG(5) SG(6) SG(7) SG(8) SG(9) SG(10)

    // wave-private LDS row: slot k = float4(xA,xB,yA,yB) for cols c0-6+2k,+1
    __shared__ float4 ls4[4][72];
    float4* lsw = ls4[wv];

    DECL_CH(CX) DECL_CH(CY) DECL_CH(CXX) DECL_CH(CYY) DECL_CH(CXY)

    // prefetch ring state
    float2 PF0mx, PF0my, PF0hx, PF0hy; float VM0 = 0.f;
    float2 PF1mx, PF1my, PF1hx, PF1hy; float VM1;
    float2 PF2mx, PF2my, PF2hx, PF2hy; float VM2;

    // prime LDS with row r0-5 (read at step 0)
    {
        const int rl = r0 - 5;
        const float fq = ((unsigned)rl < 512u) ? 1.f : 0.f;
        const int rlc = (rl < 0) ? 0 : rl;
        const float* xp = xplane + (rlc << 9);
        const float* yp = yplane + (rlc << 9);
        const float2 mx = *(const float2*)(xp + mcol), my = *(const float2*)(yp + mcol);
        const float2 hx = *(const float2*)(xp + hcolC), hy = *(const float2*)(yp + hcolC);
        const float fh = fq * hmask;
        const float2 wmx = mul2(fq, mx), wmy = mul2(fq, my);
        const float2 whx = mul2(fh, hx), why = mul2(fh, hy);
        lsw[lane + 3] = make_float4(wmx.x, wmx.y, wmy.x, wmy.y);
        if (lane < 6) lsw[hslot] = make_float4(whx.x, whx.y, why.x, why.y);
    }
    // prime PF1 <- row r0-4 (stored end of step 0), PF2 <- row r0-3 (step 1)
    {
        const int rl = r0 - 4;
        VM1 = ((unsigned)rl < 512u) ? 1.f : 0.f;
        const int rlc = (rl < 0) ? 0 : rl;
        const float* xp = xplane + (rlc << 9);
        const float* yp = yplane + (rlc << 9);
        PF1mx = *(const float2*)(xp + mcol); PF1my = *(const float2*)(yp + mcol);
        PF1hx = *(const float2*)(xp + hcolC); PF1hy = *(const float2*)(yp + hcolC);
    }
    {
        const int rl = r0 - 3;
        VM2 = ((unsigned)rl < 512u) ? 1.f : 0.f;
        const int rlc = (rl < 0) ? 0 : rl;
        const float* xp = xplane + (rlc << 9);
        const float* yp = yplane + (rlc << 9);
        PF2mx = *(const float2*)(xp + mcol); PF2my = *(const float2*)(yp + mcol);
        PF2hx = *(const float2*)(xp + hcolC); PF2hy = *(const float2*)(yp + hcolC);
    }

    float tsx = 0.f, tsy = 0.f;
    const float C1 = 1e-4f, C2 = 9e-4f;

    // 75 steps = 25 x 3 (PF ring period); emits for i in [10,74)
    #pragma unroll 1
    for (int it = 0; it < 25; ++it) {
        const int i0 = it * 3;
        STEP(i0 + 0, 0, 1)
        STEP(i0 + 1, 1, 2)
        STEP(i0 + 2, 2, 0)
    }

    // ---- block partial -> global; last block reduces all ----
    float t = tsx + tsy;
    #pragma unroll
    for (int off = 32; off > 0; off >>= 1) t += __shfl_down(t, off, 64);
    __shared__ float wsum[4];
    __shared__ int   sflag;
    if (lane == 0) wsum[wv] = t;
    __syncthreads();
    if (tid == 0) {
        partials[blockIdx.x] = (wsum[0] + wsum[1]) + (wsum[2] + wsum[3]);
        __threadfence();
        const unsigned old = atomicAdd(counter, 1u);
        sflag = (old == NBLK - 1) ? 1 : 0;
    }
    __syncthreads();
    if (sflag) {
        __threadfence();
        double s = 0.0;
        for (int idx = tid; idx < NBLK; idx += 256) s += (double)partials[idx];
        #pragma unroll
        for (int off = 32; off > 0; off >>= 1) s += __shfl_down(s, off, 64);
        __shared__ double dsum[4];
        if (lane == 0) dsum[wv] = s;
        __syncthreads();
        if (tid == 0)
            out[0] = (float)(((dsum[0] + dsum[1]) + (dsum[2] + dsum[3])) / 25165824.0);
    }
}

extern "C" void kernel_launch(void* const* d_in, const int* in_sizes, int n_in,
                              void* d_out, int out_size, void* d_ws, size_t ws_size,
                              hipStream_t stream)
{
    const float* x = (const float*)d_in[0];
    const float* y = (const float*)d_in[1];
    const float* w = (const float*)d_in[2];
    unsigned* counter = (unsigned*)d_ws;                     // zeroed below
    float* partials   = (float*)((char*)d_ws + 256);         // 768 floats

    hipMemsetAsync(d_ws, 0, 4, stream);                      // capture-safe
    ssim_fused<<<NBLK, 256, 0, stream>>>(x, y, w, counter, partials, (float*)d_out);
}

// Round 6
// 287.003 us; speedup vs baseline: 2.7425x; 2.7425x over previous
//
#include <hip/hip_runtime.h>

// SSIM on (32,3,512,512) f32 — wave-autonomous separable 11-tap streaming.
// R14: 1-col/lane, 4-chain (x-y)^2 moment basis, sized for 3 blocks/CU.
//
// Occupancy model (fits ALL R0-R4 counters): HW packs blocks by
//   floor(512 / (2 x VGPR_used)); compiler budget for "min N waves" = 512/2N.
//   120 regs -> 2 blk/CU; 84 -> 3; 64 -> 4.  => 3 blk/CU needs <=85 regs.
// R13 (conv(x^2+y^2) basis) hit the reg target but FAILED numerics
// (3.05e-4 > 2.67e-4): the combined chain accumulates magnitude <=2,
// costing 1 bit in every chain reg. R14 keeps 4 chains but tracks
//   CD = conv((x-y)^2)   (values <=1, typ ~0.17 — BETTER than conv(x^2))
// using  sx2+sy2 = [ed - (mux-muy)^2] + 2*[ep - mux*muy] = var_d + 2*sxy.
// Epilogue uses fused fmaf(-a,a,e) single-rounded cancellations (tighter
// than R0's two-rounding form), and the SSIM sum is split into 3
// accumulators (seq chains ~46 < R0's 64). Schedule unchanged from R8:
// depth-3 register PF ring, branchless clamped loads x validity-multiply,
// wave-private LDS row (float2(x,y), 74 slots), no hot-loop barriers.
// attr(3,4): budget ~84 >= ~75 live -> no spill (sentinel: WRITE~48KB);
// all 768 blocks co-resident, single phase.

#define NBLK 768

// ---- vertical shift-register chains: 10 regs x 4 quantities (scalar) ----
#define DECL_CH(C) float C##0=0.f,C##1=0.f,C##2=0.f,C##3=0.f,C##4=0.f, \
                         C##5=0.f,C##6=0.f,C##7=0.f,C##8=0.f,C##9=0.f;
// descending: each reads the not-yet-overwritten lower element
#define SHIFT(C, H) \
  C##9 = fmaf(g9, H, C##8); C##8 = fmaf(g8, H, C##7); C##7 = fmaf(g7, H, C##6); \
  C##6 = fmaf(g6, H, C##5); C##5 = fmaf(g5, H, C##4); C##4 = fmaf(g4, H, C##3); \
  C##3 = fmaf(g3, H, C##2); C##2 = fmaf(g2, H, C##1); C##1 = fmaf(g1, H, C##0); \
  C##0 = g0 * H;

// ---- horizontal tap J on LDS value QV=(x,y): accumulate 4 h-convs ----
// HX=conv(x), HY=conv(y), HD=conv((x-y)^2), HP=conv(xy)
#define HTAP(J, QV) { const float gj = g##J; \
  const float xv = (QV).x, yv = (QV).y; \
  const float t1 = gj * xv, t2 = gj * yv; \
  const float dv = xv - yv, td = gj * dv; \
  HX += t1; HY += t2; \
  HD = fmaf(td, dv, HD); \
  HP = fmaf(t1, yv, HP); }

// One step: issue PF slot P (row r0-2+i), h-conv current LDS row (r0-5+i),
// emit output row r0+i-10 if i>=10, shift chains, store PF slot Q.
#define STEP(I, P, Q, TS) { \
  const int i_ = (I); \
  const int rl = r0 - 2 + i_; \
  VM##P = ((unsigned)rl < 512u) ? 1.f : 0.f; \
  { const int rlc = (rl < 0) ? 0 : ((rl > 511) ? 511 : rl); \
    const float* xp = xplane + (rlc << 9); \
    const float* yp = yplane + (rlc << 9); \
    PF##P##mx = xp[mcol]; PF##P##my = yp[mcol]; \
    PF##P##hx = xp[hcolC]; PF##P##hy = yp[hcolC]; } \
  const float2 q0 = lsw[lane  ], q1 = lsw[lane+1], q2 = lsw[lane+2]; \
  const float2 q3 = lsw[lane+3], q4 = lsw[lane+4], q5 = lsw[lane+5]; \
  const float2 q6 = lsw[lane+6], q7 = lsw[lane+7], q8 = lsw[lane+8]; \
  const float2 q9 = lsw[lane+9], q10 = lsw[lane+10]; \
  float HX = 0.f, HY = 0.f, HD = 0.f, HP = 0.f; \
  HTAP(0,q0) HTAP(1,q1) HTAP(2,q2) HTAP(3,q3) HTAP(4,q4) HTAP(5,q5) \
  HTAP(6,q6) HTAP(7,q7) HTAP(8,q8) HTAP(9,q9) HTAP(10,q10) \
  if (i_ >= 10) { \
    const float mux = fmaf(g10, HX, CX9); \
    const float muy = fmaf(g10, HY, CY9); \
    const float ed  = fmaf(g10, HD, CD9); \
    const float ep  = fmaf(g10, HP, CP9); \
    const float mud  = mux - muy; \
    const float vard = fmaf(-mud, mud, ed);   /* var(x-y) >= 0, small */ \
    const float vp   = fmaf(-mux, muy, ep);   /* sigma_xy */ \
    const float vs   = fmaf(2.f, vp, vard);   /* sigma_x2 + sigma_y2 */ \
    const float mux2 = mux*mux, muy2 = muy*muy, muxy = mux*muy; \
    const float num = fmaf(2.f, muxy, C1) * fmaf(2.f, vp, C2); \
    const float den = (mux2 + muy2 + C1) * (vs + C2); \
    TS += num * __builtin_amdgcn_rcpf(den); \
  } \
  SHIFT(CX, HX) SHIFT(CY, HY) SHIFT(CD, HD) SHIFT(CP, HP) \
  { const float fq = VM##Q; const float fh = fq * hmask; \
    lsw[lane + 5] = make_float2(fq * PF##Q##mx, fq * PF##Q##my); \
    if (lane < 10) lsw[hslot] = make_float2(fh * PF##Q##hx, fh * PF##Q##hy); } }

__global__ __launch_bounds__(256)
__attribute__((amdgpu_waves_per_eu(3, 4)))
void ssim_fused(
    const float* __restrict__ x, const float* __restrict__ y,
    const float* __restrict__ window,
    unsigned* __restrict__ counter, float* __restrict__ partials,
    float* __restrict__ out)
{
    const int tid  = threadIdx.x;
    const int lane = tid & 63;
    // wave id is uniform: force SGPR lineage so plane pointers stay scalar
    const int wv   = __builtin_amdgcn_readfirstlane(tid >> 6);
    const int W    = blockIdx.x * 4 + wv;   // 0..3071
    const int img  = W >> 5;                // 96 planes, 32 waves each
    const int w5   = W & 31;
    const int cb   = w5 >> 2;               // 8 col bands x 64
    const int rb   = w5 & 3;                // 4 row bands x 128
    const int r0   = rb << 7;
    const int c0   = cb << 6;

    const float* xplane = x + (size_t)img * 262144;
    const float* yplane = y + (size_t)img * 262144;

    // halo geometry (time-invariant): slots 0..4 left, 69..73 right
    const int  hslot = (lane < 5) ? lane : (64 + lane);          // lanes 5..9 -> 69..73
    const int  hcol  = (lane < 5) ? (c0 - 5 + lane) : (c0 + 59 + lane);
    const float hmask = (lane < 10 && hcol >= 0 && hcol < 512) ? 1.f : 0.f;
    const int  hcolC = (hcol < 0) ? 0 : ((hcol > 511) ? 511 : hcol);
    const int  mcol  = c0 + lane;

    // 1-D gaussian (row sums of outer(g,g)); uniform -> SGPR via readfirstlane
    float gtmp[11];
    #pragma unroll
    for (int ii = 0; ii < 11; ++ii) {
        float s = 0.f;
        #pragma unroll
        for (int jj = 0; jj < 11; ++jj) s += window[ii * 11 + jj];
        gtmp[ii] = s;
    }
    #define SG(N) const float g##N = __uint_as_float(__builtin_amdgcn_readfirstlane(__float_as_uint(gtmp[N])));
    SG(0) SG(1) SG(2) SG(3) SG(4) SG(5) SG(6) SG(7) SG(8) SG(9) SG(10)

    // wave-private LDS row: slot s = float2(x,y) for col c0-5+s, s in [0,74)
    __shared__ float2 ls2[4][74];
    float2* lsw = ls2[wv];

    DECL_CH(CX) DECL_CH(CY) DECL_CH(CD) DECL_CH(CP)

    // prefetch ring state (scalar: main x,y + halo x,y)
    float PF0mx, PF0my, PF0hx, PF0hy; float VM0 = 0.f;
    float PF1mx, PF1my, PF1hx, PF1hy; float VM1;
    float PF2mx, PF2my, PF2hx, PF2hy; float VM2;

    // prime LDS with row r0-5 (read at step 0)
    {
        const int rl = r0 - 5;
        const float fq = (rl >= 0) ? 1.f : 0.f;
        const int rlc = (rl < 0) ? 0 : rl;
        const float* xp = xplane + (rlc << 9);
        const float* yp = yplane + (rlc << 9);
        const float fh = fq * hmask;
        lsw[lane + 5] = make_float2(fq * xp[mcol], fq * yp[mcol]);
        if (lane < 10) lsw[hslot] = make_float2(fh * xp[hcolC], fh * yp[hcolC]);
    }
    // prime PF1 <- row r0-4 (stored end of step 0), PF2 <- row r0-3 (step 1)
    {
        const int rl = r0 - 4;
        VM1 = (rl >= 0) ? 1.f : 0.f;
        const int rlc = (rl < 0) ? 0 : rl;
        const float* xp = xplane + (rlc << 9);
        const float* yp = yplane + (rlc << 9);
        PF1mx = xp[mcol]; PF1my = yp[mcol];
        PF1hx = xp[hcolC]; PF1hy = yp[hcolC];
    }
    {
        const int rl = r0 - 3;
        VM2 = (rl >= 0) ? 1.f : 0.f;
        const int rlc = (rl < 0) ? 0 : rl;
        const float* xp = xplane + (rlc << 9);
        const float* yp = yplane + (rlc << 9);
        PF2mx = xp[mcol]; PF2my = yp[mcol];
        PF2hx = xp[hcolC]; PF2hy = yp[hcolC];
    }

    float tsA = 0.f, tsB = 0.f, tsC = 0.f;
    const float C1 = 1e-4f, C2 = 9e-4f;

    // 138 steps = 46 x 3 (PF ring period); emits for i in [10,138)
    #pragma unroll 1
    for (int it = 0; it < 46; ++it) {
        const int i0 = it * 3;
        STEP(i0 + 0, 0, 1, tsA)
        STEP(i0 + 1, 1, 2, tsB)
        STEP(i0 + 2, 2, 0, tsC)
    }

    // ---- block partial -> global; last block reduces all ----
    float t = (tsA + tsB) + tsC;
    #pragma unroll
    for (int off = 32; off > 0; off >>= 1) t += __shfl_down(t, off, 64);
    __shared__ float wsum[4];
    __shared__ int   sflag;
    if (lane == 0) wsum[wv] = t;
    __syncthreads();
    if (tid == 0) {
        partials[blockIdx.x] = (wsum[0] + wsum[1]) + (wsum[2] + wsum[3]);
        __threadfence();
        const unsigned old = atomicAdd(counter, 1u);
        sflag = (old == NBLK - 1) ? 1 : 0;
    }
    __syncthreads();
    if (sflag) {
        __threadfence();
        double s = 0.0;
        for (int idx = tid; idx < NBLK; idx += 256) s += (double)partials[idx];
        #pragma unroll
        for (int off = 32; off > 0; off >>= 1) s += __shfl_down(s, off, 64);
        __shared__ double dsum[4];
        if (lane == 0) dsum[wv] = s;
        __syncthreads();
        if (tid == 0)
            out[0] = (float)(((dsum[0] + dsum[1]) + (dsum[2] + dsum[3])) / 25165824.0);
    }
}

extern "C" void kernel_launch(void* const* d_in, const int* in_sizes, int n_in,
                              void* d_out, int out_size, void* d_ws, size_t ws_size,
                              hipStream_t stream)
{
    const float* x = (const float*)d_in[0];
    const float* y = (const float*)d_in[1];
    const float* w = (const float*)d_in[2];
    unsigned* counter = (unsigned*)d_ws;                     // zeroed below
    float* partials   = (float*)((char*)d_ws + 256);         // 768 floats

    hipMemsetAsync(d_ws, 0, 4, stream);                      // capture-safe
    ssim_fused<<<NBLK, 256, 0, stream>>>(x, y, w, counter, partials, (float*)d_out);
}